// Round 7
// baseline (340.440 us; speedup 1.0000x reference)
//
#include <hip/hip_runtime.h>
#include <hip/hip_bf16.h>
#include <float.h>

// Problem constants
#define N_ROWS 32768          // 32 * 1024 query vectors
#define DIMS   64
#define K_EMB  8192
#define NT     (K_EMB / 16)   // 512 column tiles of 16
#define KQ     4              // K split into quarters
#define NTQ    (NT / KQ)      // 128 tiles per quarter (7-bit tile id)
#define TSTAGE 4              // tiles per stage = 16 KB
#define NSTAGE (NTQ / TSTAGE) // 32
// split-bf16 err ~6.5e-4 + 2x 7-bit mantissa-steal (|f|<64 -> 1e-3 each)
#define GAP_THR 4.0e-3f

typedef __attribute__((ext_vector_type(8))) short s8v;   // 8 bf16 (A/B frag)
typedef __attribute__((ext_vector_type(4))) float f4v;   // C/D frag
typedef __attribute__((ext_vector_type(4))) int   i4v;   // 16B load unit

// Workspace layout (bytes) — ~3.6 MB
#define WS_EFRAG 0                               // 512 tiles * 4KB = 2 MiB
#define WS_EN2B4 (2 * 1024 * 1024)               // 8192 * float4 broadcast = 128 KB
#define WS_IDX   (WS_EN2B4 + K_EMB * 16)         // 32768 i32
#define WS_BH    (WS_IDX + N_ROWS * 4)           // [KQ][N] best (packed f32)
#define WS_SH    (WS_BH + KQ * N_ROWS * 4)       // [KQ][N] second
#define WS_CH    (WS_SH + KQ * N_ROWS * 4)       // [KQ][N] col (u16)
#define WS_CTL   (WS_CH + KQ * N_ROWS * 2)       // {double loss; int done}

// Output layout (float32 elements): [quantized | loss | indices]
#define OUT_LOSS (N_ROWS * DIMS)
#define OUT_IDX  (N_ROWS * DIMS + 1)

__device__ inline short bfh(float v) {
    __hip_bfloat16 h = __float2bfloat16(v);
    return __builtin_bit_cast(short, h);
}
__device__ inline float bff(short s) {
    __hip_bfloat16 h = __builtin_bit_cast(__hip_bfloat16, s);
    return __bfloat162float(h);
}

// ---------------------------------------------------------------------------
// Prep: embeddings -> 16x16x32 MFMA B-frag layout (hi/lo bf16 split) and
// en2b4[col] = float4 broadcast of -0.5*||e||^2 (direct MFMA C operand).
// B-frag: lane holds B[k=(lane>>4)*8+j][n=lane&15]. Frags: 0=hi k[0,32),
// 1=hi k[32,64), 2=lo k[0,32), 3=lo k[32,64). [tile][frag][lane][16B].
// ---------------------------------------------------------------------------
__global__ void vq_prep(const float* __restrict__ emb, short* __restrict__ efrag,
                        f4v* __restrict__ en2b4) {
    int gid = blockIdx.x * 256 + threadIdx.x;   // NT*64 = 32768 threads
    int t = gid >> 6, lane = gid & 63;
    int m = lane & 15, q = lane >> 4;
    const float* er = emb + (size_t)(t * 16 + m) * DIMS;
    s8v hi0, lo0, hi1, lo1;
    float ss = 0.f;
#pragma unroll
    for (int j = 0; j < 8; ++j) {
        float v0 = er[q * 8 + j];
        float v1 = er[32 + q * 8 + j];
        ss += v0 * v0 + v1 * v1;
        short h0 = bfh(v0); lo0[j] = bfh(v0 - bff(h0)); hi0[j] = h0;
        short h1 = bfh(v1); lo1[j] = bfh(v1 - bff(h1)); hi1[j] = h1;
    }
    s8v* base = (s8v*)efrag + (size_t)t * 4 * 64;
    base[0 * 64 + lane] = hi0;
    base[1 * 64 + lane] = hi1;
    base[2 * 64 + lane] = lo0;
    base[3 * 64 + lane] = lo1;
    ss += __shfl_xor(ss, 16, 64);
    ss += __shfl_xor(ss, 32, 64);
    if (q == 0) {
        float c = -0.5f * ss;
        f4v cv = {c, c, c, c};
        en2b4[t * 16 + m] = cv;
    }
}

// ---------------------------------------------------------------------------
// Phase 1: LDS-staged split-bf16 16x16x32 MFMA + paired med3/max3 argmax.
// Grid (128, 4): x = row-block (4 waves x 64 rows = 256), y = K-quarter.
// 4 row-groups per wave share each B ds_read; tile id (7b) embedded in the
// low mantissa bits; C operand loaded directly from en2b4 (no acc-init movs).
// ---------------------------------------------------------------------------
__global__ __launch_bounds__(256, 2) void vq_phase1(
    const float* __restrict__ x, const short* __restrict__ efrag,
    const f4v* __restrict__ en2b4,
    float* __restrict__ bh, float* __restrict__ sh,
    unsigned short* __restrict__ ch) {
    __shared__ __align__(16) char lds[2][TSTAGE * 4096];   // 32 KB
    int tid = threadIdx.x, wid = tid >> 6, lane = tid & 63;
    int m = lane & 15, q = lane >> 4;
    int kq = blockIdx.y;
    int row0 = blockIdx.x * 256 + wid * 64;

    // A-frags for 4 row-groups: A[m][k=quad*8+j], hi/lo, two K-halves of dims.
    s8v ahi[4][2], alo[4][2];
#pragma unroll
    for (int g = 0; g < 4; ++g) {
        const float* xr = x + (size_t)(row0 + g * 16 + m) * DIMS + q * 8;
#pragma unroll
        for (int j = 0; j < 8; ++j) {
            float v0 = xr[j], v1 = xr[32 + j];
            short h0 = bfh(v0); alo[g][0][j] = bfh(v0 - bff(h0)); ahi[g][0][j] = h0;
            short h1 = bfh(v1); alo[g][1][j] = bfh(v1 - bff(h1)); ahi[g][1][j] = h1;
        }
    }

    float best[4][4], sec[4][4];
#pragma unroll
    for (int g = 0; g < 4; ++g)
#pragma unroll
        for (int r = 0; r < 4; ++r) { best[g][r] = -FLT_MAX; sec[g][r] = -FLT_MAX; }

    const char* gsrc = (const char*)efrag + (size_t)kq * NTQ * 4096;
    const f4v* en2q = en2b4 + (size_t)kq * (K_EMB / KQ);

    // preload stage 0 (16 KB)
#pragma unroll
    for (int i = 0; i < 4; ++i)
        __builtin_amdgcn_global_load_lds(
            (const __attribute__((address_space(1))) void*)(gsrc + i * 4096 + tid * 16),
            (__attribute__((address_space(3))) void*)(&lds[0][i * 4096 + tid * 16]),
            16, 0, 0);
    __syncthreads();

    for (int s = 0; s < NSTAGE; ++s) {
        int pb = s & 1;
        if (s + 1 < NSTAGE) {
            const char* gn = gsrc + (size_t)(s + 1) * TSTAGE * 4096;
#pragma unroll
            for (int i = 0; i < 4; ++i)
                __builtin_amdgcn_global_load_lds(
                    (const __attribute__((address_space(1))) void*)(gn + i * 4096 + tid * 16),
                    (__attribute__((address_space(3))) void*)(&lds[pb ^ 1][i * 4096 + tid * 16]),
                    16, 0, 0);
        }
        const i4v* B = (const i4v*)(lds[pb]);
#pragma unroll
        for (int tp = 0; tp < TSTAGE; tp += 2) {   // tile pair
            int t0 = s * TSTAGE + tp;              // tile within quarter
            i4v ba0 = B[(tp + 0) * 256 +   0 + lane];
            i4v ba1 = B[(tp + 0) * 256 +  64 + lane];
            i4v ba2 = B[(tp + 0) * 256 + 128 + lane];
            i4v ba3 = B[(tp + 0) * 256 + 192 + lane];
            i4v bb0 = B[(tp + 1) * 256 +   0 + lane];
            i4v bb1 = B[(tp + 1) * 256 +  64 + lane];
            i4v bb2 = B[(tp + 1) * 256 + 128 + lane];
            i4v bb3 = B[(tp + 1) * 256 + 192 + lane];
            f4v c0a = en2q[(size_t)(t0 + 0) * 16 + m];   // C init, no movs
            f4v c0b = en2q[(size_t)(t0 + 1) * 16 + m];
            int tba = (~(t0 + 0)) & 0x7F;
            int tbb = (~(t0 + 1)) & 0x7F;
#pragma unroll
            for (int g = 0; g < 4; ++g) {
                f4v aa = __builtin_amdgcn_mfma_f32_16x16x32_bf16(ahi[g][0], __builtin_bit_cast(s8v, ba0), c0a, 0, 0, 0);
                f4v ab = __builtin_amdgcn_mfma_f32_16x16x32_bf16(ahi[g][0], __builtin_bit_cast(s8v, bb0), c0b, 0, 0, 0);
                aa = __builtin_amdgcn_mfma_f32_16x16x32_bf16(ahi[g][1], __builtin_bit_cast(s8v, ba1), aa, 0, 0, 0);
                ab = __builtin_amdgcn_mfma_f32_16x16x32_bf16(ahi[g][1], __builtin_bit_cast(s8v, bb1), ab, 0, 0, 0);
                aa = __builtin_amdgcn_mfma_f32_16x16x32_bf16(ahi[g][0], __builtin_bit_cast(s8v, ba2), aa, 0, 0, 0);
                ab = __builtin_amdgcn_mfma_f32_16x16x32_bf16(ahi[g][0], __builtin_bit_cast(s8v, bb2), ab, 0, 0, 0);
                aa = __builtin_amdgcn_mfma_f32_16x16x32_bf16(ahi[g][1], __builtin_bit_cast(s8v, ba3), aa, 0, 0, 0);
                ab = __builtin_amdgcn_mfma_f32_16x16x32_bf16(ahi[g][1], __builtin_bit_cast(s8v, bb3), ab, 0, 0, 0);
                aa = __builtin_amdgcn_mfma_f32_16x16x32_bf16(alo[g][0], __builtin_bit_cast(s8v, ba0), aa, 0, 0, 0);
                ab = __builtin_amdgcn_mfma_f32_16x16x32_bf16(alo[g][0], __builtin_bit_cast(s8v, bb0), ab, 0, 0, 0);
                aa = __builtin_amdgcn_mfma_f32_16x16x32_bf16(alo[g][1], __builtin_bit_cast(s8v, ba1), aa, 0, 0, 0);
                ab = __builtin_amdgcn_mfma_f32_16x16x32_bf16(alo[g][1], __builtin_bit_cast(s8v, bb1), ab, 0, 0, 0);
#pragma unroll
                for (int r = 0; r < 4; ++r) {   // same row for aa[r], ab[r]
                    float v0 = __int_as_float((__float_as_int(aa[r]) & 0xFFFFFF80) | tba);
                    float v1 = __int_as_float((__float_as_int(ab[r]) & 0xFFFFFF80) | tbb);
                    float ob = best[g][r];
                    sec[g][r]  = fmaxf(sec[g][r], __builtin_amdgcn_fmed3f(v0, v1, ob));
                    best[g][r] = fmaxf(fmaxf(v0, v1), ob);
                }
            }
        }
        __syncthreads();
    }

    // Reduce (best, col, sec) across the 16 col-lanes of each quad.
#pragma unroll
    for (int g = 0; g < 4; ++g)
#pragma unroll
    for (int r = 0; r < 4; ++r) {
        float b = best[g][r], s2 = sec[g][r];
        int c = ((~__float_as_int(b)) & 0x7F) * 16 + m;   // col within quarter
#pragma unroll
        for (int off = 1; off < 16; off <<= 1) {
            float ob = __shfl_xor(b, off, 64);
            float os = __shfl_xor(s2, off, 64);
            int   oc = __shfl_xor(c, off, 64);
            float nb = fmaxf(b, ob);
            float ns = fmaxf(fminf(b, ob), fmaxf(s2, os));
            bool take = (ob > b) || (ob == b && oc < c);  // tie -> lowest col
            c = take ? oc : c;
            b = nb; s2 = ns;
        }
        if (m == 0) {
            int row = row0 + g * 16 + q * 4 + r;
            int o = kq * N_ROWS + row;
            bh[o] = b; sh[o] = s2;
            ch[o] = (unsigned short)(kq * (K_EMB / KQ) + c);
        }
    }
}

// ---------------------------------------------------------------------------
// Fused merge + fixup: each block owns 32 rows. Merge the 4 K-quarter
// partials, write idx, and exactly rescan (fp32) its own flagged rows.
// ---------------------------------------------------------------------------
__global__ __launch_bounds__(256) void vq_fix(
    const float* __restrict__ x, const float* __restrict__ emb,
    const f4v* __restrict__ en2b4,
    const float* __restrict__ bh, const float* __restrict__ sh,
    const unsigned short* __restrict__ ch, int* __restrict__ idx_buf) {
    __shared__ int flg[32];
    __shared__ int nflg;
    __shared__ float4 sx[16];
    __shared__ float sbf[4];
    __shared__ int   sbc[4];
    int tid = threadIdx.x, wid = tid >> 6, lane = tid & 63;
    int row0 = blockIdx.x * 32;
    if (tid == 0) nflg = 0;
    __syncthreads();
    if (tid < 32) {
        int row = row0 + tid;
        float b[KQ], s[KQ];
        int c[KQ];
#pragma unroll
        for (int qq = 0; qq < KQ; ++qq) {
            b[qq] = bh[qq * N_ROWS + row];
            s[qq] = sh[qq * N_ROWS + row];
            c[qq] = ch[qq * N_ROWS + row];
        }
        int ci = 0;
        float bb = b[0];
#pragma unroll
        for (int qq = 1; qq < KQ; ++qq)
            if (b[qq] > bb) { bb = b[qq]; ci = qq; }   // tie -> lowest quarter
        float ss = -FLT_MAX;
#pragma unroll
        for (int qq = 0; qq < KQ; ++qq) {
            ss = fmaxf(ss, s[qq]);
            if (qq != ci) ss = fmaxf(ss, b[qq]);
        }
        idx_buf[row] = c[ci];
        if (bb - ss < GAP_THR) {
            int p = atomicAdd(&nflg, 1);
            flg[p] = row;
        }
    }
    __syncthreads();
    int cnt = nflg;
    for (int i = 0; i < cnt; ++i) {
        int row = flg[i];
        if (tid < 16) sx[tid] = ((const float4*)(x + (size_t)row * DIMS))[tid];
        __syncthreads();
        float bf_ = -FLT_MAX;
        int bc_ = 0;
        for (int c = tid; c < K_EMB; c += 256) {
            const float4* er = (const float4*)(emb + (size_t)c * DIMS);
            float d = 0.f;
#pragma unroll
            for (int qq = 0; qq < 16; ++qq) {
                float4 e = er[qq];
                float4 xx = sx[qq];
                d += e.x * xx.x + e.y * xx.y + e.z * xx.z + e.w * xx.w;
            }
            float f = d + en2b4[c].x;
            if (f > bf_) { bf_ = f; bc_ = c; }   // ascending c -> first occurrence
        }
#pragma unroll
        for (int off = 1; off < 64; off <<= 1) {
            float of = __shfl_xor(bf_, off, 64);
            int   oc = __shfl_xor(bc_, off, 64);
            if (of > bf_ || (of == bf_ && oc < bc_)) { bf_ = of; bc_ = oc; }
        }
        if (lane == 0) { sbf[wid] = bf_; sbc[wid] = bc_; }
        __syncthreads();
        if (tid == 0) {
            float b = sbf[0]; int c = sbc[0];
#pragma unroll
            for (int k = 1; k < 4; ++k)
                if (sbf[k] > b || (sbf[k] == b && sbc[k] < c)) { b = sbf[k]; c = sbc[k]; }
            idx_buf[row] = c;
        }
        __syncthreads();
    }
}

// ---------------------------------------------------------------------------
// Gather quantized rows, squared error, indices; last block finalizes loss.
// ---------------------------------------------------------------------------
__global__ void vq_gather(const float* __restrict__ x, const float* __restrict__ emb,
                          const int* __restrict__ idx_buf,
                          float* __restrict__ out, double* __restrict__ loss_acc,
                          int* __restrict__ done_ctr) {
    int row = blockIdx.x * blockDim.x + threadIdx.x;
    int idx = idx_buf[row];
    const float4* ev = (const float4*)(emb + (size_t)idx * DIMS);
    const float4* xv = (const float4*)(x + (size_t)row * DIMS);
    float4* ov = (float4*)(out + (size_t)row * DIMS);
    float s = 0.f;
#pragma unroll
    for (int qq = 0; qq < 16; ++qq) {
        float4 ee = ev[qq];
        float4 xx = xv[qq];
        float dx = ee.x - xx.x, dy = ee.y - xx.y, dz = ee.z - xx.z, dw = ee.w - xx.w;
        s += dx * dx + dy * dy + dz * dz + dw * dw;
        ov[qq] = ee;
    }
#pragma unroll
    for (int off = 32; off > 0; off >>= 1) s += __shfl_down(s, off, 64);
    if ((threadIdx.x & 63) == 0) atomicAdd(loss_acc, (double)s);
    out[OUT_IDX + row] = (float)idx;
    __syncthreads();
    if (threadIdx.x == 0) {
        __threadfence();
        int d = atomicAdd(done_ctr, 1);
        if (d == (int)gridDim.x - 1) {
            double tot = atomicAdd(loss_acc, 0.0);
            out[OUT_LOSS] = (float)(1.25 * tot / (double)(N_ROWS * DIMS));
        }
    }
}

// ---------------------------------------------------------------------------
extern "C" void kernel_launch(void* const* d_in, const int* in_sizes, int n_in,
                              void* d_out, int out_size, void* d_ws, size_t ws_size,
                              hipStream_t stream) {
    const float* x   = (const float*)d_in[0];
    const float* emb = (const float*)d_in[1];
    float* out = (float*)d_out;
    char*  ws  = (char*)d_ws;

    short* efrag = (short*)(ws + WS_EFRAG);
    f4v*   en2b4 = (f4v*)(ws + WS_EN2B4);
    int*   idx_buf = (int*)(ws + WS_IDX);
    float* bhb   = (float*)(ws + WS_BH);
    float* shb   = (float*)(ws + WS_SH);
    unsigned short* chb = (unsigned short*)(ws + WS_CH);
    double* loss_acc = (double*)(ws + WS_CTL);
    int*    done_ctr = (int*)(ws + WS_CTL + 8);

    hipMemsetAsync(ws + WS_CTL, 0, 16, stream);   // loss + done

    vq_prep<<<(NT * 64) / 256, 256, 0, stream>>>(emb, efrag, en2b4);      // 128 blocks
    vq_phase1<<<dim3(N_ROWS / 256, KQ), 256, 0, stream>>>(x, efrag, en2b4, bhb, shb, chb);
    vq_fix<<<N_ROWS / 32, 256, 0, stream>>>(x, emb, en2b4, bhb, shb, chb, idx_buf);
    vq_gather<<<N_ROWS / 256, 256, 0, stream>>>(x, emb, idx_buf, out, loss_acc, done_ctr);
}

// Round 8
// 213.263 us; speedup vs baseline: 1.5963x; 1.5963x over previous
//
#include <hip/hip_runtime.h>
#include <hip/hip_bf16.h>
#include <float.h>

// Problem constants
#define N_ROWS 32768          // 32 * 1024 query vectors
#define DIMS   64
#define K_EMB  8192
#define NT     (K_EMB / 16)   // 512 column tiles of 16
#define KQ     4              // K split into quarters
#define NTQ    (NT / KQ)      // 128 tiles per quarter (7-bit tile id)
#define TSTAGE 8              // tiles per stage = 32 KB
#define NSTAGE (NTQ / TSTAGE) // 16
// steal(7b, |f|<128) 2e-3 x2 values + split-bf16 1.3e-3 => 5.3e-3 bound
#define GAP_THR 6.0e-3f

typedef __attribute__((ext_vector_type(8))) short s8v;   // 8 bf16 (A/B frag)
typedef __attribute__((ext_vector_type(4))) float f4v;   // C/D frag
typedef __attribute__((ext_vector_type(4))) int   i4v;   // 16B load unit

// Workspace layout (bytes) — ~3.4 MB
#define WS_EFRAG 0                               // 512 tiles * 4KB = 2 MiB
#define WS_EN2B4 (2 * 1024 * 1024)               // 8192 * float4 = 128 KB
#define WS_IDX   (WS_EN2B4 + K_EMB * 16)         // 32768 i32
#define WS_KEY   (WS_IDX + N_ROWS * 4)           // 32768 u64 fixup keys
#define WS_BH    (WS_KEY + N_ROWS * 8)           // [KQ][N] best (packed f32)
#define WS_SH    (WS_BH + KQ * N_ROWS * 4)       // [KQ][N] second
#define WS_CH    (WS_SH + KQ * N_ROWS * 4)       // [KQ][N] col (u16)
#define WS_CTL   (WS_CH + KQ * N_ROWS * 2)       // {double loss; int wl; int done}
#define WS_WL    (WS_CTL + 16)                   // worklist

// Output layout (float32 elements): [quantized | loss | indices]
#define OUT_LOSS (N_ROWS * DIMS)
#define OUT_IDX  (N_ROWS * DIMS + 1)

__device__ inline short bfh(float v) {
    __hip_bfloat16 h = __float2bfloat16(v);
    return __builtin_bit_cast(short, h);
}
__device__ inline float bff(short s) {
    __hip_bfloat16 h = __builtin_bit_cast(__hip_bfloat16, s);
    return __bfloat162float(h);
}

// ---------------------------------------------------------------------------
// Prep: embeddings -> 16x16x32 B-frag layout (hi/lo bf16 split) and
// en2b4[col] = float4 broadcast of -0.5*||e||^2 (direct MFMA C operand).
// B-frag: lane holds B[k=(lane>>4)*8+j][n=lane&15]. Frags: 0=hi k[0,32),
// 1=hi k[32,64), 2=lo k[0,32), 3=lo k[32,64). [tile][frag][lane][16B].
// ---------------------------------------------------------------------------
__global__ void vq_prep(const float* __restrict__ emb, short* __restrict__ efrag,
                        f4v* __restrict__ en2b4) {
    int gid = blockIdx.x * 256 + threadIdx.x;   // NT*64 = 32768 threads
    int t = gid >> 6, lane = gid & 63;
    int m = lane & 15, q = lane >> 4;
    const float* er = emb + (size_t)(t * 16 + m) * DIMS;
    s8v hi0, lo0, hi1, lo1;
    float ss = 0.f;
#pragma unroll
    for (int j = 0; j < 8; ++j) {
        float v0 = er[q * 8 + j];
        float v1 = er[32 + q * 8 + j];
        ss += v0 * v0 + v1 * v1;
        short h0 = bfh(v0); lo0[j] = bfh(v0 - bff(h0)); hi0[j] = h0;
        short h1 = bfh(v1); lo1[j] = bfh(v1 - bff(h1)); hi1[j] = h1;
    }
    s8v* base = (s8v*)efrag + (size_t)t * 4 * 64;
    base[0 * 64 + lane] = hi0;
    base[1 * 64 + lane] = hi1;
    base[2 * 64 + lane] = lo0;
    base[3 * 64 + lane] = lo1;
    ss += __shfl_xor(ss, 16, 64);
    ss += __shfl_xor(ss, 32, 64);
    if (q == 0) {
        float c = -0.5f * ss;
        f4v cv = {c, c, c, c};
        en2b4[t * 16 + m] = cv;
    }
}

// ---------------------------------------------------------------------------
// Phase 1: LDS-staged split-bf16 16x16x32 MFMA, 3-op packed argmax epilogue.
// Grid (128, KQ): x = row-block (4 waves x 64 rows = 256), y = K-quarter.
// 4 row-groups share each B ds_read; C operand comes straight from en2b4;
// 7-bit tile id lives in the low mantissa bits (and_or / med3 / max).
// ---------------------------------------------------------------------------
__global__ __launch_bounds__(256, 2) void vq_phase1(
    const float* __restrict__ x, const short* __restrict__ efrag,
    const f4v* __restrict__ en2b4,
    float* __restrict__ bh, float* __restrict__ sh,
    unsigned short* __restrict__ ch) {
    __shared__ __align__(16) char lds[2][TSTAGE * 4096];   // 64 KB
    int tid = threadIdx.x, wid = tid >> 6, lane = tid & 63;
    int m = lane & 15, q = lane >> 4;
    int kq = blockIdx.y;
    int row0 = blockIdx.x * 256 + wid * 64;

    // A-frags for 4 row-groups: A[m][k=quad*8+j], hi/lo, two K-halves of dims.
    s8v ahi[4][2], alo[4][2];
#pragma unroll
    for (int g = 0; g < 4; ++g) {
        const float* xr = x + (size_t)(row0 + g * 16 + m) * DIMS + q * 8;
#pragma unroll
        for (int j = 0; j < 8; ++j) {
            float v0 = xr[j], v1 = xr[32 + j];
            short h0 = bfh(v0); alo[g][0][j] = bfh(v0 - bff(h0)); ahi[g][0][j] = h0;
            short h1 = bfh(v1); alo[g][1][j] = bfh(v1 - bff(h1)); ahi[g][1][j] = h1;
        }
    }

    float best[4][4], sec[4][4];
#pragma unroll
    for (int g = 0; g < 4; ++g)
#pragma unroll
        for (int r = 0; r < 4; ++r) { best[g][r] = -FLT_MAX; sec[g][r] = -FLT_MAX; }

    const char* gsrc = (const char*)efrag + (size_t)kq * NTQ * 4096;
    const f4v* en2q = en2b4 + (size_t)kq * (K_EMB / KQ);

    // preload stage 0 (32 KB)
#pragma unroll
    for (int i = 0; i < 8; ++i)
        __builtin_amdgcn_global_load_lds(
            (const __attribute__((address_space(1))) void*)(gsrc + i * 4096 + tid * 16),
            (__attribute__((address_space(3))) void*)(&lds[0][i * 4096 + tid * 16]),
            16, 0, 0);
    __syncthreads();

    for (int s = 0; s < NSTAGE; ++s) {
        int pb = s & 1;
        if (s + 1 < NSTAGE) {
            const char* gn = gsrc + (size_t)(s + 1) * TSTAGE * 4096;
#pragma unroll
            for (int i = 0; i < 8; ++i)
                __builtin_amdgcn_global_load_lds(
                    (const __attribute__((address_space(1))) void*)(gn + i * 4096 + tid * 16),
                    (__attribute__((address_space(3))) void*)(&lds[pb ^ 1][i * 4096 + tid * 16]),
                    16, 0, 0);
        }
        const i4v* B = (const i4v*)(lds[pb]);
#pragma unroll
        for (int tt = 0; tt < TSTAGE; ++tt) {
            int t8 = s * TSTAGE + tt;               // tile within quarter
            i4v b0 = B[tt * 256 +   0 + lane];
            i4v b1 = B[tt * 256 +  64 + lane];
            i4v b2 = B[tt * 256 + 128 + lane];
            i4v b3 = B[tt * 256 + 192 + lane];
            f4v c0 = en2q[(size_t)t8 * 16 + m];     // C init, no movs
            int tb = (~t8) & 0x7F;
#pragma unroll
            for (int g = 0; g < 4; ++g) {
                f4v a = __builtin_amdgcn_mfma_f32_16x16x32_bf16(ahi[g][0], __builtin_bit_cast(s8v, b0), c0, 0, 0, 0);
                a = __builtin_amdgcn_mfma_f32_16x16x32_bf16(ahi[g][1], __builtin_bit_cast(s8v, b1), a, 0, 0, 0);
                a = __builtin_amdgcn_mfma_f32_16x16x32_bf16(ahi[g][0], __builtin_bit_cast(s8v, b2), a, 0, 0, 0);
                a = __builtin_amdgcn_mfma_f32_16x16x32_bf16(ahi[g][1], __builtin_bit_cast(s8v, b3), a, 0, 0, 0);
                a = __builtin_amdgcn_mfma_f32_16x16x32_bf16(alo[g][0], __builtin_bit_cast(s8v, b0), a, 0, 0, 0);
                a = __builtin_amdgcn_mfma_f32_16x16x32_bf16(alo[g][1], __builtin_bit_cast(s8v, b1), a, 0, 0, 0);
#pragma unroll
                for (int r = 0; r < 4; ++r) {   // C/D: col=lane&15, row=quad*4+r
                    float v = __int_as_float((__float_as_int(a[r]) & 0xFFFFFF80) | tb);
                    sec[g][r]  = __builtin_amdgcn_fmed3f(v, best[g][r], sec[g][r]);
                    best[g][r] = fmaxf(best[g][r], v);
                }
            }
        }
        __syncthreads();
    }

    // Reduce (best, col, sec) across the 16 col-lanes of each quad.
#pragma unroll
    for (int g = 0; g < 4; ++g)
#pragma unroll
    for (int r = 0; r < 4; ++r) {
        float b = best[g][r], s2 = sec[g][r];
        int c = ((~__float_as_int(b)) & 0x7F) * 16 + m;   // col within quarter
#pragma unroll
        for (int off = 1; off < 16; off <<= 1) {
            float ob = __shfl_xor(b, off, 64);
            float os = __shfl_xor(s2, off, 64);
            int   oc = __shfl_xor(c, off, 64);
            float nb = fmaxf(b, ob);
            float ns = fmaxf(fminf(b, ob), fmaxf(s2, os));
            bool take = (ob > b) || (ob == b && oc < c);  // tie -> lowest col
            c = take ? oc : c;
            b = nb; s2 = ns;
        }
        if (m == 0) {
            int row = row0 + g * 16 + q * 4 + r;
            int o = kq * N_ROWS + row;
            bh[o] = b; sh[o] = s2;
            ch[o] = (unsigned short)(kq * (K_EMB / KQ) + c);
        }
    }
}

// ---------------------------------------------------------------------------
// Merge the KQ quarters per row; zero fixup keys; build compact worklist.
// ---------------------------------------------------------------------------
__global__ void vq_merge(const float* __restrict__ bh, const float* __restrict__ sh,
                         const unsigned short* __restrict__ ch, int* __restrict__ idx_buf,
                         unsigned long long* __restrict__ key8,
                         int* __restrict__ wl, int* __restrict__ wl_count) {
    int row = blockIdx.x * 256 + threadIdx.x;
    float b[KQ], s[KQ];
    int c[KQ];
#pragma unroll
    for (int qq = 0; qq < KQ; ++qq) {
        b[qq] = bh[qq * N_ROWS + row];
        s[qq] = sh[qq * N_ROWS + row];
        c[qq] = ch[qq * N_ROWS + row];
    }
    int ci = 0;
    float bb = b[0];
#pragma unroll
    for (int qq = 1; qq < KQ; ++qq)
        if (b[qq] > bb) { bb = b[qq]; ci = qq; }   // tie -> lowest quarter
    float ss = -FLT_MAX;
#pragma unroll
    for (int qq = 0; qq < KQ; ++qq) {
        ss = fmaxf(ss, s[qq]);
        if (qq != ci) ss = fmaxf(ss, b[qq]);
    }
    idx_buf[row] = c[ci];
    key8[row] = 0ULL;
    if (bb - ss < GAP_THR) {
        int pos = atomicAdd(wl_count, 1);
        wl[pos] = row;
    }
}

// ---------------------------------------------------------------------------
// Fixup: exact fp32 rescan, 8 col-chunk blocks per flagged row, merged via
// atomicMax on packed (sortable(f) << 32 | ~idx) — exact, ties -> low idx.
// ---------------------------------------------------------------------------
__global__ __launch_bounds__(256) void vq_fixup(
    const float* __restrict__ x, const float* __restrict__ emb,
    const f4v* __restrict__ en2b4, unsigned long long* __restrict__ key8,
    const int* __restrict__ wl, const int* __restrict__ wl_count) {
    __shared__ float4 sx[16];
    __shared__ float sbf[4];
    __shared__ int   sbc[4];
    int tid = threadIdx.x, wid = tid >> 6, lane = tid & 63;
    int cnt = *wl_count;
    for (int wi = blockIdx.x; wi < cnt * 8; wi += gridDim.x) {
        int row = wl[wi >> 3];
        int cbase = (wi & 7) * (K_EMB / 8);
        if (tid < 16) sx[tid] = ((const float4*)(x + (size_t)row * DIMS))[tid];
        __syncthreads();
        float bf_ = -FLT_MAX;
        int bc_ = 0;
        for (int c = cbase + tid; c < cbase + K_EMB / 8; c += 256) {
            const float4* er = (const float4*)(emb + (size_t)c * DIMS);
            float d = 0.f;
#pragma unroll
            for (int qq = 0; qq < 16; ++qq) {
                float4 e = er[qq];
                float4 xx = sx[qq];
                d += e.x * xx.x + e.y * xx.y + e.z * xx.z + e.w * xx.w;
            }
            float f = d + en2b4[c].x;
            if (f > bf_) { bf_ = f; bc_ = c; }   // ascending c -> first occurrence
        }
#pragma unroll
        for (int off = 1; off < 64; off <<= 1) {
            float of = __shfl_xor(bf_, off, 64);
            int   oc = __shfl_xor(bc_, off, 64);
            if (of > bf_ || (of == bf_ && oc < bc_)) { bf_ = of; bc_ = oc; }
        }
        if (lane == 0) { sbf[wid] = bf_; sbc[wid] = bc_; }
        __syncthreads();
        if (tid == 0) {
            float b = sbf[0]; int c = sbc[0];
#pragma unroll
            for (int i = 1; i < 4; ++i)
                if (sbf[i] > b || (sbf[i] == b && sbc[i] < c)) { b = sbf[i]; c = sbc[i]; }
            unsigned int u = __float_as_uint(b);
            unsigned int sb = ((int)u < 0) ? ~u : (u | 0x80000000u);
            unsigned long long key = ((unsigned long long)sb << 32) | (unsigned int)(~c);
            atomicMax(&key8[row], key);
        }
        __syncthreads();
    }
}

// ---------------------------------------------------------------------------
// Gather quantized rows, squared error, indices; last block finalizes loss.
// ---------------------------------------------------------------------------
__global__ void vq_gather(const float* __restrict__ x, const float* __restrict__ emb,
                          const int* __restrict__ idx_buf,
                          const unsigned long long* __restrict__ key8,
                          float* __restrict__ out, double* __restrict__ loss_acc,
                          int* __restrict__ done_ctr) {
    int row = blockIdx.x * blockDim.x + threadIdx.x;
    unsigned long long k = key8[row];
    int idx = k ? (int)(~(unsigned int)k) : idx_buf[row];
    const float4* ev = (const float4*)(emb + (size_t)idx * DIMS);
    const float4* xv = (const float4*)(x + (size_t)row * DIMS);
    float4* ov = (float4*)(out + (size_t)row * DIMS);
    float s = 0.f;
#pragma unroll
    for (int qq = 0; qq < 16; ++qq) {
        float4 ee = ev[qq];
        float4 xx = xv[qq];
        float dx = ee.x - xx.x, dy = ee.y - xx.y, dz = ee.z - xx.z, dw = ee.w - xx.w;
        s += dx * dx + dy * dy + dz * dz + dw * dw;
        ov[qq] = ee;
    }
#pragma unroll
    for (int off = 32; off > 0; off >>= 1) s += __shfl_down(s, off, 64);
    if ((threadIdx.x & 63) == 0) atomicAdd(loss_acc, (double)s);
    out[OUT_IDX + row] = (float)idx;
    __syncthreads();
    if (threadIdx.x == 0) {
        __threadfence();
        int d = atomicAdd(done_ctr, 1);
        if (d == (int)gridDim.x - 1) {
            double tot = atomicAdd(loss_acc, 0.0);
            out[OUT_LOSS] = (float)(1.25 * tot / (double)(N_ROWS * DIMS));
        }
    }
}

// ---------------------------------------------------------------------------
extern "C" void kernel_launch(void* const* d_in, const int* in_sizes, int n_in,
                              void* d_out, int out_size, void* d_ws, size_t ws_size,
                              hipStream_t stream) {
    const float* x   = (const float*)d_in[0];
    const float* emb = (const float*)d_in[1];
    float* out = (float*)d_out;
    char*  ws  = (char*)d_ws;

    short* efrag = (short*)(ws + WS_EFRAG);
    f4v*   en2b4 = (f4v*)(ws + WS_EN2B4);
    int*   idx_buf = (int*)(ws + WS_IDX);
    unsigned long long* key8 = (unsigned long long*)(ws + WS_KEY);
    float* bhb   = (float*)(ws + WS_BH);
    float* shb   = (float*)(ws + WS_SH);
    unsigned short* chb = (unsigned short*)(ws + WS_CH);
    double* loss_acc = (double*)(ws + WS_CTL);
    int*   wl_count  = (int*)(ws + WS_CTL + 8);
    int*   done_ctr  = (int*)(ws + WS_CTL + 12);
    int*   wl        = (int*)(ws + WS_WL);

    hipMemsetAsync(ws + WS_CTL, 0, 16, stream);   // loss + wl_count + done

    vq_prep<<<(NT * 64) / 256, 256, 0, stream>>>(emb, efrag, en2b4);      // 128 blocks
    vq_phase1<<<dim3(N_ROWS / 256, KQ), 256, 0, stream>>>(x, efrag, en2b4, bhb, shb, chb);
    vq_merge<<<N_ROWS / 256, 256, 0, stream>>>(bhb, shb, chb, idx_buf, key8, wl, wl_count);
    vq_fixup<<<2048, 256, 0, stream>>>(x, emb, en2b4, key8, wl, wl_count);
    vq_gather<<<N_ROWS / 256, 256, 0, stream>>>(x, emb, idx_buf, key8, out, loss_acc, done_ctr);
}